// Round 7
// baseline (211.221 us; speedup 1.0000x reference)
//
#include <hip/hip_runtime.h>
#include <math.h>

// (B,S,D,C) = (64, 576, 768, 200)
#define Bsz  64
#define Ssz  576
#define Dsz  768
#define Csz  200
#define NPAD 208        // 13 tiles of 16: 0..199 classes, col 200 = ones (rowsum), rest zero
#define MT   64         // rows per block; grid 576 (9 blocks per batch, never crosses batch)
#define BK   32
#define NKT  24         // 768 / 32

typedef short short8 __attribute__((ext_vector_type(8)));
typedef float f32x4  __attribute__((ext_vector_type(4)));

#define AS_GLOBAL __attribute__((address_space(1)))
#define AS_LDS    __attribute__((address_space(3)))

__device__ inline unsigned short f2bf_rne(float f) {
    union { float f; unsigned int u; } v; v.f = f;
    return (unsigned short)((v.u + 0x7FFFu + ((v.u >> 16) & 1u)) >> 16);
}
// two fp32 -> packed bf16x2 (round-half-up): low16 = lo, high16 = hi
__device__ inline unsigned int pack2bf(float lo, float hi) {
    union { float f; unsigned int u; } a, b; a.f = lo; b.f = hi;
    return __builtin_amdgcn_perm(b.u + 0x8000u, a.u + 0x8000u, 0x07060302u);
}
// async 16B-per-lane global -> LDS (dest = wave-uniform base + lane*16)
__device__ inline void gload16(const unsigned short* g, unsigned short* l) {
    __builtin_amdgcn_global_load_lds((const AS_GLOBAL unsigned int*)g,
                                     (AS_LDS unsigned int*)l, 16, 0, 0);
}
__device__ inline void gload16f(const float* g, float* l) {
    __builtin_amdgcn_global_load_lds((const AS_GLOBAL unsigned int*)g,
                                     (AS_LDS unsigned int*)l, 16, 0, 0);
}

// one-time: W (200x768 fp32) -> bf16 (208x768); row 200 = 1.0 (rowsum), 201..207 = 0
__global__ __launch_bounds__(256) void prep_w(const float* __restrict__ W,
                                              unsigned short* __restrict__ Wb) {
    const int i   = blockIdx.x * 256 + threadIdx.x;
    const int row = i / (Dsz / 4);
    const int col = (i % (Dsz / 4)) * 4;
    ushort4 h;
    if (row < Csz) {
        const float4 v = *(const float4*)(W + (size_t)row * Dsz + col);
        h.x = f2bf_rne(v.x); h.y = f2bf_rne(v.y); h.z = f2bf_rne(v.z); h.w = f2bf_rne(v.w);
    } else if (row == Csz) {
        h.x = h.y = h.z = h.w = 0x3F80;   // bf16 1.0
    } else {
        h.x = h.y = h.z = h.w = 0;
    }
    *(ushort4*)(Wb + (size_t)row * Dsz + col) = h;
}

// global classifier runs FIRST: out[b,c] = ct[b]·gw[c] + gb[c]
__global__ __launch_bounds__(256) void gc_kernel(
    const float* __restrict__ ct, const float* __restrict__ gw,
    const float* __restrict__ gb, float* __restrict__ out) {
    const int b    = blockIdx.x;
    const int wv   = threadIdx.x >> 6;
    const int lane = threadIdx.x & 63;
    const int c    = blockIdx.y * 4 + wv;
    const float* wr = gw + (size_t)c * Dsz + lane * 12;
    const float* cr = ct + (size_t)b * Dsz + lane * 12;
    float s = 0.f;
#pragma unroll
    for (int j = 0; j < 3; ++j) {
        const float4 w = *(const float4*)(wr + 4 * j);
        const float4 x = *(const float4*)(cr + 4 * j);
        s += w.x * x.x + w.y * x.y + w.z * x.z + w.w * x.w;
    }
#pragma unroll
    for (int off = 32; off > 0; off >>= 1) s += __shfl_down(s, off, 64);
    if (lane == 0) out[b * Csz + c] = s + gb[c];
}

// MT=64, BK=32, all-DMA dbuf, 1 barrier/iter. Wave w owns row-tile w (16 rows) x all 13
// class-tiles. Staged bytes per block: X 196KB + W 312KB (vs R6: X 98K + W 638K per 32 rows).
__global__ __launch_bounds__(256, 3) void attn_kernel(
    const float* __restrict__ X,            // (B*S, D) fp32
    const unsigned short* __restrict__ Wb,  // (NPAD, D) bf16
    const float* __restrict__ attn_b,       // (C,)
    const float* __restrict__ lam,          // (1,)
    float* __restrict__ out)                // (B, C): gscore already written
{
    __shared__ float sX[2][MT * BK];               // 2 x 8 KB (512 16B-chunks each)
    __shared__ unsigned short sW[2][NPAD * BK];    // 2 x 13 KB (832 chunks each)

    const int tid  = threadIdx.x;
    const int lane = tid & 63;
    const int w    = tid >> 6;
    const int m    = lane & 15;
    const int q    = lane >> 4;
    const int rowbase = blockIdx.x * MT;
    const int bidx    = rowbase / Ssz;

    // ---- X DMA map: 512 chunks (row = s>>3, 8 chunks/row of 4 floats), wave w: slots
    // [w*128, w*128+128) as two instrs. Swizzle: slot s holds global chunk (s&7)^(row&7).
    const int sxa  = w * 128 + lane;
    const int xrow = sxa >> 3;
    const int xgc  = (sxa & 7) ^ (xrow & 7);        // invariant under row += 8
    const float* xg = X + (size_t)(rowbase + xrow) * Dsz + xgc * 4;

    // ---- W DMA map: 832 chunks (row = s>>2, 4 chunks/row of 8 bf16), 13 groups of 64,
    // waves take 3/3/3/4. Swizzle: slot s holds global chunk (s&3)^(row&3).
    const int wn    = (w < 3) ? 3 : 4;
    const int grp0  = w * 3;
    const int sw0   = grp0 * 64 + lane;
    const int wrow0 = sw0 >> 2;
    const int wgc   = (sw0 & 3) ^ (wrow0 & 3);      // invariant under row += 16
    const unsigned short* wg = Wb + (size_t)wrow0 * Dsz + wgc * 8;

    // ---- LDS read offsets (fixed per lane)
    const int rA    = w * 16 + m;
    const int aoff0 = (rA * 8 + ((2 * q) ^ (rA & 7))) * 4;      // floats
    const int aoff1 = (rA * 8 + ((2 * q + 1) ^ (rA & 7))) * 4;
    const int boff  = (m * 4 + (q ^ (m & 3))) * 8;              // shorts; + t*512

    f32x4 acc[13];
#pragma unroll
    for (int t = 0; t < 13; ++t) acc[t] = (f32x4){0.f, 0.f, 0.f, 0.f};

    // ---- prologue: tile 0 into buffer 0
    gload16f(xg, &sX[0][w * 512]);
    gload16f(xg + 8 * Dsz, &sX[0][w * 512 + 256]);
#pragma unroll
    for (int j = 0; j < 4; ++j)
        if (j < wn) gload16(wg + (size_t)16 * j * Dsz, &sW[0][(grp0 + j) * 512]);

    for (int kt = 0; kt < NKT; ++kt) {
        const int p = kt & 1;
        // barrier drain: buffer p's DMA (issued last iter) complete; p^1 free to restage
        __syncthreads();
        if (kt + 1 < NKT) {
            const int kk = (kt + 1) * BK;
            gload16f(xg + kk, &sX[p ^ 1][w * 512]);
            gload16f(xg + kk + 8 * Dsz, &sX[p ^ 1][w * 512 + 256]);
#pragma unroll
            for (int j = 0; j < 4; ++j)
                if (j < wn) gload16(wg + (size_t)(kk + 16 * j * Dsz), &sW[p ^ 1][(grp0 + j) * 512]);
        }
        // ---- A frag from LDS fp32 (+ convert), 13 B frags, 13 MFMA (K=32)
        const float4 alo = *(const float4*)&sX[p][aoff0];
        const float4 ahi = *(const float4*)&sX[p][aoff1];
        union { short8 s; unsigned int u[4]; } A;
        A.u[0] = pack2bf(alo.x, alo.y); A.u[1] = pack2bf(alo.z, alo.w);
        A.u[2] = pack2bf(ahi.x, ahi.y); A.u[3] = pack2bf(ahi.z, ahi.w);
#pragma unroll
        for (int t = 0; t < 13; ++t) {
            const short8 bf = *(const short8*)&sW[p][boff + t * 512];
            acc[t] = __builtin_amdgcn_mfma_f32_16x16x32_bf16(A.s, bf, acc[t], 0, 0, 0);
        }
    }

    // ---- rowsum via ones-column: tile 12 col 200 => lanes m==8, rows q*4+r (wave-local)
    float rsv[4];
#pragma unroll
    for (int r = 0; r < 4; ++r) rsv[r] = __shfl(acc[12][r], (lane & 48) + 8, 64);

    const float scale = lam[0] * (1.f / ((float)Ssz * (float)Dsz));

    // ---- epilogue: C/D col = lane&15, row = q*4+reg; reduce wave's 16 rows, atomic add
#pragma unroll
    for (int t = 0; t < 13; ++t) {
        const int c = t * 16 + m;
        if (c < Csz) {
            const float bias = attn_b[c];
            float s = 0.f;
#pragma unroll
            for (int r = 0; r < 4; ++r)
                s += rsv[r] / (1.f + __expf(-(acc[t][r] + bias)));
            s += __shfl_xor(s, 16, 64);
            s += __shfl_xor(s, 32, 64);
            if (q == 0) atomicAdd(&out[bidx * Csz + c], s * scale);
        }
    }
}

extern "C" void kernel_launch(void* const* d_in, const int* in_sizes, int n_in,
                              void* d_out, int out_size, void* d_ws, size_t ws_size,
                              hipStream_t stream) {
    const float* X   = (const float*)d_in[0];
    const float* ct  = (const float*)d_in[1];
    const float* aw  = (const float*)d_in[2];
    const float* ab  = (const float*)d_in[3];
    const float* gw  = (const float*)d_in[4];
    const float* gb  = (const float*)d_in[5];
    const float* lam = (const float*)d_in[6];
    float* out = (float*)d_out;
    unsigned short* Wb = (unsigned short*)d_ws;   // 208*768*2 = 320 KB

    prep_w<<<(NPAD * Dsz / 4) / 256, 256, 0, stream>>>(aw, Wb);
    gc_kernel<<<dim3(Bsz, Csz / 4), 256, 0, stream>>>(ct, gw, gb, out);
    attn_kernel<<<(Bsz * Ssz) / MT, 256, 0, stream>>>(X, Wb, ab, lam, out);
}